// Round 1
// baseline (2173.608 us; speedup 1.0000x reference)
//
#include <hip/hip_runtime.h>
#include <math.h>

#define BATCH 16
#define CIN 103
#define CCONV 256
#define NOUT 103
#define DOUT 16
#define RECSZ 8343
#define H1SZ 5562
#define H2SZ 12514

// ws float offsets
#define WS_P      0         // 16*256
#define WS_SQ     4096      // 16*256
#define WS_WSUM   8192      // 256*103*16 = 421888
#define WS_BB     430080    // 103*256 = 26368
#define WS_S      456448    // 16*103*16 = 26368
#define WS_FACTOR 482816    // 256
#define WS_F0     483072    // f0 TRANSPOSED [1648][16] = 26368
#define WS_F1     509440    // f1 TRANSPOSED [5562][16] = 88992
#define WS_F2     598432    // f2 TRANSPOSED [12514][16] = 200224
#define WS_PART1  798656    // fc1 partials: 42 * 88992  = 3737664
#define WS_PART2  4536320   // fc2 partials: 39 * 200224 = 7808736
#define WS_PART3  12345056  // fc3 partials: 61 * 133488 = 8142768
// total = 20487824 floats = 78.2 MB (ws is poison-filled at ~1.6 GB, plenty)

// ---------------- init: bb = 1 (biases now folded into fcred_k) ----------------
__global__ __launch_bounds__(256) void init_bb_k(float* __restrict__ bb) {
    int i = blockIdx.x * 256 + threadIdx.x;
    if (i < 103 * 256) bb[i] = 1.0f;
}

// ---------------- conv (VALID 3x3) + relu + mean pool -> p[b][co] ----------------
__global__ __launch_bounds__(256) void conv_pool_k(const float* __restrict__ x,
                                                   const float* __restrict__ w,
                                                   const float* __restrict__ cb,
                                                   float* __restrict__ p) {
    int b = blockIdx.x >> 6;
    int cob = (blockIdx.x & 63) << 2;
    __shared__ float xs[CIN * 81];
    int t = threadIdx.x;
    for (int i = t; i < CIN * 81; i += 256) xs[i] = x[(size_t)b * CIN * 81 + i];
    __syncthreads();
    int wave = t >> 6, lane = t & 63;
    int co = cob + wave;
    co = __builtin_amdgcn_readfirstlane(co);
    int pos = lane < 49 ? lane : 0;
    int oh = pos / 7, ow = pos % 7;
    const float* wp = w + (size_t)co * CIN * 9;
    const float* xp = xs + oh * 9 + ow;
    float acc = 0.f;
    for (int ci = 0; ci < CIN; ++ci) {
#pragma unroll
        for (int kh = 0; kh < 3; ++kh)
#pragma unroll
            for (int kw = 0; kw < 3; ++kw)
                acc = fmaf(xp[ci * 81 + kh * 9 + kw], wp[ci * 9 + kh * 3 + kw], acc);
    }
    acc += cb[co];
    acc = fmaxf(acc, 0.f);
    if (lane >= 49) acc = 0.f;
#pragma unroll
    for (int off = 32; off; off >>= 1) acc += __shfl_down(acc, off);
    if (lane == 0) p[b * 256 + co] = acc * (1.0f / 49.0f);
}

// ---------------- squash p over c -> sq[b][c] ----------------
__global__ __launch_bounds__(256) void squash_p_k(const float* __restrict__ p, float* __restrict__ sq) {
    int b = blockIdx.x, c = threadIdx.x;
    float v = p[b * 256 + c];
    float ss = v * v;
#pragma unroll
    for (int off = 32; off; off >>= 1) ss += __shfl_down(ss, off);
    __shared__ float red[4];
    if ((c & 63) == 0) red[c >> 6] = ss;
    __syncthreads();
    float ms = red[0] + red[1] + red[2] + red[3];
    float mag = sqrtf(ms);
    sq[b * 256 + c] = v * mag / (1.f + ms);
}

// ---------------- Wsum[c][j][o] = sum_i W_caps[c][j][o][i] ----------------
__global__ __launch_bounds__(256) void wsum_k(const float* __restrict__ Wc, float* __restrict__ wsum) {
    int idx = blockIdx.x * 256 + threadIdx.x;
    const float4* p4 = (const float4*)(Wc + (size_t)idx * 32);
    float s = 0.f;
#pragma unroll
    for (int q = 0; q < 8; ++q) { float4 v = p4[q]; s += v.x + v.y + v.z + v.w; }
    wsum[idx] = s;
}

// ---------------- routing: softmax over c + s[b][j][o] ----------------
__global__ __launch_bounds__(256) void route_s_k(const float* __restrict__ sq,
                                                 const float* __restrict__ wsum,
                                                 const float* __restrict__ bb,
                                                 float* __restrict__ s_out) {
    int j = blockIdx.x;
    int t = threadIdx.x;
    __shared__ float sqst[4096];
    __shared__ float wls[4096];
    __shared__ float cc[256];
    __shared__ float red[8];
    float bv = bb[j * 256 + t];
    for (int i = t; i < 4096; i += 256) {
        sqst[i] = sq[((i & 15) << 8) + (i >> 4)];
        wls[i] = wsum[(size_t)(i >> 4) * (103 * 16) + j * 16 + (i & 15)];
    }
    int wave = t >> 6, lane = t & 63;
    float m = bv;
#pragma unroll
    for (int off = 32; off; off >>= 1) m = fmaxf(m, __shfl_down(m, off));
    if (lane == 0) red[wave] = m;
    __syncthreads();
    m = fmaxf(fmaxf(red[0], red[1]), fmaxf(red[2], red[3]));
    float e = expf(bv - m);
    float ssum = e;
#pragma unroll
    for (int off = 32; off; off >>= 1) ssum += __shfl_down(ssum, off);
    if (lane == 0) red[4 + wave] = ssum;
    __syncthreads();
    ssum = red[4] + red[5] + red[6] + red[7];
    cc[t] = e / ssum;
    __syncthreads();
    for (int i = t; i < 4096; i += 256) sqst[i] *= cc[i >> 4];
    __syncthreads();
    int b = t >> 4, o = t & 15;
    float acc = 0.f;
    for (int c = 0; c < 256; ++c)
        acc = fmaf(sqst[c * 16 + b], wls[c * 16 + o], acc);
    s_out[((size_t)b * 103 + j) * 16 + o] = acc;
}

// ---------------- squash factor over j: factor[b][o] ----------------
__global__ __launch_bounds__(256) void factor_k(const float* __restrict__ s, float* __restrict__ factor) {
    int t = threadIdx.x;
    int b = t >> 4, o = t & 15;
    float ms = 0.f;
    for (int j = 0; j < 103; ++j) {
        float v = s[((size_t)b * 103 + j) * 16 + o];
        ms = fmaf(v, v, ms);
    }
    factor[t] = sqrtf(ms) / (1.f + ms);
}

// ---------------- agreement + bb update ----------------
__global__ __launch_bounds__(256) void route_upd_k(const float* __restrict__ sq,
                                                   const float* __restrict__ wsum,
                                                   const float* __restrict__ s,
                                                   const float* __restrict__ factor,
                                                   float* __restrict__ bb) {
    int j = blockIdx.x;
    int t = threadIdx.x;
    __shared__ float vs[256];
    {
        int b = t >> 4, o = t & 15;
        vs[t] = s[((size_t)b * 103 + j) * 16 + o] * factor[t];
    }
    __syncthreads();
    const float4* wp = (const float4*)(wsum + ((size_t)t * 103 + j) * 16);
    float4 w0 = wp[0], w1 = wp[1], w2 = wp[2], w3 = wp[3];
    float wv[16] = {w0.x, w0.y, w0.z, w0.w, w1.x, w1.y, w1.z, w1.w,
                    w2.x, w2.y, w2.z, w2.w, w3.x, w3.y, w3.z, w3.w};
    float acc = 0.f;
#pragma unroll
    for (int b = 0; b < 16; ++b) {
        float d = 0.f;
#pragma unroll
        for (int o = 0; o < 16; ++o) d = fmaf(wv[o], vs[b * 16 + o], d);
        acc = fmaf(sq[b * 256 + t], d, acc);
    }
    bb[j * 256 + t] += acc * (1.0f / 16.0f);
}

// ---------------- final v, ba output, f0t[(j*16+o)*16 + b] = v*ba (TRANSPOSED) ----------------
__global__ __launch_bounds__(256) void final_v_k(const float* __restrict__ s,
                                                 const float* __restrict__ factor,
                                                 float* __restrict__ out_ba,
                                                 float* __restrict__ f0t) {
    int idx = blockIdx.x * 256 + threadIdx.x;
    if (idx >= 16 * 103) return;
    int b = idx / 103;
    int j = idx - b * 103;
    const float4* sp = (const float4*)(s + (size_t)idx * 16);
    float4 s0 = sp[0], s1 = sp[1], s2 = sp[2], s3 = sp[3];
    float sv[16] = {s0.x, s0.y, s0.z, s0.w, s1.x, s1.y, s1.z, s1.w,
                    s2.x, s2.y, s2.z, s2.w, s3.x, s3.y, s3.z, s3.w};
    float v[16];
    float nrm2 = 0.f;
#pragma unroll
    for (int o = 0; o < 16; ++o) {
        v[o] = sv[o] * factor[b * 16 + o];
        nrm2 = fmaf(v[o], v[o], nrm2);
    }
    float ba = sqrtf(nrm2);
    out_ba[idx] = ba;
    // f0 transposed: [k=j*16+o][b]
    float* fp = f0t + ((size_t)j << 8) + b;
#pragma unroll
    for (int o = 0; o < 16; ++o) fp[o << 4] = v[o] * ba;
}

// ---------------- FC: partial[b][n] = sum_{k in chunk} in_t[k][b] * w[k][n] ----------------
// in_t is [K][16] (transposed activations -> contiguous LDS staging).
// Thread handles 2 adjacent cols, all 16 batches in registers.
// Software pipeline: 8-row weight groups, two named register buffers (A/B),
// group g+1 loads issued before group g compute -> 8-16 loads in flight/wave.
// Output: plain stores to per-y-block partial slab (NO atomics); fcred_k sums + bias.
// OUT_T: partial layout [n][16] (coalesced per-thread dwordx4) for fc1/fc2;
//        fc3 keeps [b][N] (final recon layout).
#define FC_LOADG(b0, b1, kk)                                          \
    {                                                                 \
        const float* wq = wp + (size_t)(kk) * Ns;                     \
        if (V2) {                                                     \
            _Pragma("unroll")                                         \
            for (int r = 0; r < 8; ++r) {                             \
                float2 q = *(const float2*)(wq + (size_t)r * Ns);     \
                b0[r] = q.x; b1[r] = q.y;                             \
            }                                                         \
        } else {                                                      \
            _Pragma("unroll")                                         \
            for (int r = 0; r < 8; ++r) {                             \
                b0[r] = wq[(size_t)r * Ns];                           \
                b1[r] = wq[(size_t)r * Ns + off1];                    \
            }                                                         \
        }                                                             \
    }

#define FC_COMP(b0, b1, kk)                                           \
    {                                                                 \
        _Pragma("unroll")                                             \
        for (int r = 0; r < 8; ++r) {                                 \
            const float* s0 = sact + (((kk) + r) << 4);               \
            _Pragma("unroll")                                         \
            for (int bq = 0; bq < 16; ++bq) {                         \
                float v = s0[bq];                                     \
                a0[bq] = fmaf(v, b0[r], a0[bq]);                      \
                a1[bq] = fmaf(v, b1[r], a1[bq]);                      \
            }                                                         \
        }                                                             \
    }

template <bool V2, bool OUT_T>
__global__ __launch_bounds__(256, 4) void fc_k(const float* __restrict__ in,
                                               const float* __restrict__ w,
                                               float* __restrict__ part,
                                               int K, int N, int kchunk) {
    extern __shared__ float sact[];   // [nk][16]
    const int k0 = blockIdx.y * kchunk;
    int nk = K - k0; if (nk > kchunk) nk = kchunk;
    // contiguous coalesced staging (in is [K][16])
    for (int i = threadIdx.x; i < (nk << 4); i += 256)
        sact[i] = in[((size_t)k0 << 4) + i];
    __syncthreads();

    const int c0 = blockIdx.x * 512 + (threadIdx.x << 1);
    const bool st0 = c0 < N;
    const bool st1 = c0 + 1 < N;
    const int c = st0 ? c0 : 0;          // clamp OOB threads (stores guarded)
    const int off1 = st1 ? 1 : 0;        // odd-N tail: duplicate col (a1 discarded)
    const float* wp = w + (size_t)k0 * N + c;
    const size_t Ns = (size_t)N;

    float a0[16], a1[16];
#pragma unroll
    for (int b = 0; b < 16; ++b) { a0[b] = 0.f; a1[b] = 0.f; }

    int k = 0;
    {
        const int ng = nk >> 3;          // full 8-row groups
        if (ng > 0) {
            float A0[8], A1[8], B0[8], B1[8];
            FC_LOADG(A0, A1, 0);
            int g = 0;
            for (; g + 2 <= ng; g += 2) {
                FC_LOADG(B0, B1, (g + 1) << 3);
                FC_COMP(A0, A1, g << 3);
                if (g + 2 < ng) FC_LOADG(A0, A1, (g + 2) << 3);
                FC_COMP(B0, B1, (g + 1) << 3);
            }
            if (g < ng) FC_COMP(A0, A1, g << 3);
            k = ng << 3;
        }
    }
    for (; k < nk; ++k) {                // tail rows (<8)
        float wv0, wv1;
        if (V2) { float2 q = *(const float2*)(wp + (size_t)k * Ns); wv0 = q.x; wv1 = q.y; }
        else    { wv0 = wp[(size_t)k * Ns]; wv1 = wp[(size_t)k * Ns + off1]; }
        const float* s0 = sact + (k << 4);
#pragma unroll
        for (int b = 0; b < 16; ++b) {
            a0[b] = fmaf(s0[b], wv0, a0[b]);
            a1[b] = fmaf(s0[b], wv1, a1[b]);
        }
    }

    float* po = part + (size_t)blockIdx.y * (Ns << 4);
    if (OUT_T) {
        // [n][16]: 16 consecutive floats per col -> dwordx4 stores
        if (st0) {
            float* q = po + ((size_t)c << 4);
#pragma unroll
            for (int b = 0; b < 16; ++b) q[b] = a0[b];
        }
        if (st1) {
            float* q = po + ((size_t)(c + 1) << 4);
#pragma unroll
            for (int b = 0; b < 16; ++b) q[b] = a1[b];
        }
    } else {
        // [b][N]: wave writes 128 consecutive floats per b
        if (st0) {
#pragma unroll
            for (int b = 0; b < 16; ++b) po[(size_t)b * Ns + c] = a0[b];
        }
        if (st1) {
#pragma unroll
            for (int b = 0; b < 16; ++b) po[(size_t)b * Ns + c + 1] = a1[b];
        }
    }
}

// ---------------- reduce partials + bias ----------------
// T: out/partials are [n][16], bias idx i>>4 ; else [b][N], bias idx i%N
template <bool T>
__global__ __launch_bounds__(256) void fcred_k(const float* __restrict__ P,
                                               const float* __restrict__ bias,
                                               float* __restrict__ out,
                                               int total, int ny, int N) {
    int i = blockIdx.x * 256 + threadIdx.x;
    if (i >= total) return;
    float sv = T ? bias[i >> 4] : bias[i % N];
    const float* p = P + i;
    for (int y = 0; y < ny; ++y) sv += p[(size_t)y * total];
    out[i] = sv;
}

extern "C" void kernel_launch(void* const* d_in, const int* in_sizes, int n_in,
                              void* d_out, int out_size, void* d_ws, size_t ws_size,
                              hipStream_t stream) {
    const float* x      = (const float*)d_in[0];
    const float* conv_w = (const float*)d_in[1];
    const float* conv_b = (const float*)d_in[2];
    const float* W_caps = (const float*)d_in[3];
    const float* fc1_w  = (const float*)d_in[4];
    const float* fc1_b  = (const float*)d_in[5];
    const float* fc2_w  = (const float*)d_in[6];
    const float* fc2_b  = (const float*)d_in[7];
    const float* fc3_w  = (const float*)d_in[8];
    const float* fc3_b  = (const float*)d_in[9];
    float* out = (float*)d_out;
    float* ws  = (float*)d_ws;

    float* p      = ws + WS_P;
    float* sq     = ws + WS_SQ;
    float* wsum   = ws + WS_WSUM;
    float* bb     = ws + WS_BB;
    float* s      = ws + WS_S;
    float* factor = ws + WS_FACTOR;
    float* f0     = ws + WS_F0;
    float* f1     = ws + WS_F1;
    float* f2     = ws + WS_F2;
    float* part1  = ws + WS_PART1;
    float* part2  = ws + WS_PART2;
    float* part3  = ws + WS_PART3;
    float* ba_out = out;            // 1648
    float* recon  = out + 1648;     // 133488

    init_bb_k<<<103, 256, 0, stream>>>(bb);

    conv_pool_k<<<1024, 256, 0, stream>>>(x, conv_w, conv_b, p);
    squash_p_k<<<16, 256, 0, stream>>>(p, sq);
    wsum_k<<<1648, 256, 0, stream>>>(W_caps, wsum);

    for (int it = 0; it < 3; ++it) {
        route_s_k<<<103, 256, 0, stream>>>(sq, wsum, bb, s);
        factor_k<<<1, 256, 0, stream>>>(s, factor);
        if (it < 2)
            route_upd_k<<<103, 256, 0, stream>>>(sq, wsum, s, factor, bb);
    }
    final_v_k<<<7, 256, 0, stream>>>(s, factor, ba_out, f0);

    // fc1: (16,1648)@(1648,5562); kchunk=40 (mult of 8), y=42, blocks=462
    fc_k<true, true><<<dim3(11, 42), 256, 40 * 64, stream>>>(f0, fc1_w, part1, 1648, H1SZ, 40);
    fcred_k<true><<<348, 256, 0, stream>>>(part1, fc1_b, f1, 16 * H1SZ, 42, H1SZ);

    // fc2: (16,5562)@(5562,12514); kchunk=144, y=39, blocks=975 (~4/CU)
    fc_k<true, true><<<dim3(25, 39), 256, 144 * 64, stream>>>(f1, fc2_w, part2, H1SZ, H2SZ, 144);
    fcred_k<true><<<783, 256, 0, stream>>>(part2, fc2_b, f2, 16 * H2SZ, 39, H2SZ);

    // fc3: (16,12514)@(12514,8343); odd N -> scalar pair; kchunk=208, y=61, blocks=1037
    fc_k<false, false><<<dim3(17, 61), 256, 208 * 64, stream>>>(f2, fc3_w, part3, H2SZ, RECSZ, 208);
    fcred_k<false><<<522, 256, 0, stream>>>(part3, fc3_b, recon, 16 * RECSZ, 61, RECSZ);
}

// Round 2
// 986.248 us; speedup vs baseline: 2.2039x; 2.2039x over previous
//
#include <hip/hip_runtime.h>
#include <math.h>

#define BATCH 16
#define CIN 103
#define CCONV 256
#define NOUT 103
#define DOUT 16
#define RECSZ 8343
#define H1SZ 5562
#define H2SZ 12514

// ws float offsets
#define WS_P      0         // 16*256
#define WS_SQ     4096      // 16*256
#define WS_WSUM   8192      // 256*103*16 = 421888
#define WS_BB     430080    // 103*256 = 26368
#define WS_S      456448    // 16*103*16 = 26368
#define WS_FACTOR 482816    // 256
#define WS_F0     483072    // f0 TRANSPOSED [1648][16] = 26368
#define WS_F1     509440    // f1 TRANSPOSED [5562][16] = 88992
#define WS_F2     598432    // f2 TRANSPOSED [12514][16] = 200224
#define WS_PART1  798656    // fc1 partials: 42 * 88992  = 3737664
#define WS_PART2  4536320   // fc2 partials: 39 * 200224 = 7808736
#define WS_PART3  12345056  // fc3 partials: 61 * 133488 = 8142768

// ---------------- init: bb = 1 (biases folded into fcred_k) ----------------
__global__ __launch_bounds__(256) void init_bb_k(float* __restrict__ bb) {
    int i = blockIdx.x * 256 + threadIdx.x;
    if (i < 103 * 256) bb[i] = 1.0f;
}

// ---------------- conv (VALID 3x3) + relu + mean pool -> p[b][co] ----------------
__global__ __launch_bounds__(256) void conv_pool_k(const float* __restrict__ x,
                                                   const float* __restrict__ w,
                                                   const float* __restrict__ cb,
                                                   float* __restrict__ p) {
    int b = blockIdx.x >> 6;
    int cob = (blockIdx.x & 63) << 2;
    __shared__ float xs[CIN * 81];
    int t = threadIdx.x;
    for (int i = t; i < CIN * 81; i += 256) xs[i] = x[(size_t)b * CIN * 81 + i];
    __syncthreads();
    int wave = t >> 6, lane = t & 63;
    int co = cob + wave;
    co = __builtin_amdgcn_readfirstlane(co);
    int pos = lane < 49 ? lane : 0;
    int oh = pos / 7, ow = pos % 7;
    const float* wp = w + (size_t)co * CIN * 9;
    const float* xp = xs + oh * 9 + ow;
    float acc = 0.f;
    for (int ci = 0; ci < CIN; ++ci) {
#pragma unroll
        for (int kh = 0; kh < 3; ++kh)
#pragma unroll
            for (int kw = 0; kw < 3; ++kw)
                acc = fmaf(xp[ci * 81 + kh * 9 + kw], wp[ci * 9 + kh * 3 + kw], acc);
    }
    acc += cb[co];
    acc = fmaxf(acc, 0.f);
    if (lane >= 49) acc = 0.f;
#pragma unroll
    for (int off = 32; off; off >>= 1) acc += __shfl_down(acc, off);
    if (lane == 0) p[b * 256 + co] = acc * (1.0f / 49.0f);
}

// ---------------- squash p over c -> sq[b][c] ----------------
__global__ __launch_bounds__(256) void squash_p_k(const float* __restrict__ p, float* __restrict__ sq) {
    int b = blockIdx.x, c = threadIdx.x;
    float v = p[b * 256 + c];
    float ss = v * v;
#pragma unroll
    for (int off = 32; off; off >>= 1) ss += __shfl_down(ss, off);
    __shared__ float red[4];
    if ((c & 63) == 0) red[c >> 6] = ss;
    __syncthreads();
    float ms = red[0] + red[1] + red[2] + red[3];
    float mag = sqrtf(ms);
    sq[b * 256 + c] = v * mag / (1.f + ms);
}

// ---------------- Wsum[c][j][o] = sum_i W_caps[c][j][o][i] ----------------
__global__ __launch_bounds__(256) void wsum_k(const float* __restrict__ Wc, float* __restrict__ wsum) {
    int idx = blockIdx.x * 256 + threadIdx.x;
    const float4* p4 = (const float4*)(Wc + (size_t)idx * 32);
    float s = 0.f;
#pragma unroll
    for (int q = 0; q < 8; ++q) { float4 v = p4[q]; s += v.x + v.y + v.z + v.w; }
    wsum[idx] = s;
}

// ---------------- routing: softmax over c + s[b][j][o] ----------------
__global__ __launch_bounds__(256) void route_s_k(const float* __restrict__ sq,
                                                 const float* __restrict__ wsum,
                                                 const float* __restrict__ bb,
                                                 float* __restrict__ s_out) {
    int j = blockIdx.x;
    int t = threadIdx.x;
    __shared__ float sqst[4096];
    __shared__ float wls[4096];
    __shared__ float cc[256];
    __shared__ float red[8];
    float bv = bb[j * 256 + t];
    for (int i = t; i < 4096; i += 256) {
        sqst[i] = sq[((i & 15) << 8) + (i >> 4)];
        wls[i] = wsum[(size_t)(i >> 4) * (103 * 16) + j * 16 + (i & 15)];
    }
    int wave = t >> 6, lane = t & 63;
    float m = bv;
#pragma unroll
    for (int off = 32; off; off >>= 1) m = fmaxf(m, __shfl_down(m, off));
    if (lane == 0) red[wave] = m;
    __syncthreads();
    m = fmaxf(fmaxf(red[0], red[1]), fmaxf(red[2], red[3]));
    float e = expf(bv - m);
    float ssum = e;
#pragma unroll
    for (int off = 32; off; off >>= 1) ssum += __shfl_down(ssum, off);
    if (lane == 0) red[4 + wave] = ssum;
    __syncthreads();
    ssum = red[4] + red[5] + red[6] + red[7];
    cc[t] = e / ssum;
    __syncthreads();
    for (int i = t; i < 4096; i += 256) sqst[i] *= cc[i >> 4];
    __syncthreads();
    int b = t >> 4, o = t & 15;
    float acc = 0.f;
    for (int c = 0; c < 256; ++c)
        acc = fmaf(sqst[c * 16 + b], wls[c * 16 + o], acc);
    s_out[((size_t)b * 103 + j) * 16 + o] = acc;
}

// ---------------- squash factor over j: factor[b][o] ----------------
__global__ __launch_bounds__(256) void factor_k(const float* __restrict__ s, float* __restrict__ factor) {
    int t = threadIdx.x;
    int b = t >> 4, o = t & 15;
    float ms = 0.f;
    for (int j = 0; j < 103; ++j) {
        float v = s[((size_t)b * 103 + j) * 16 + o];
        ms = fmaf(v, v, ms);
    }
    factor[t] = sqrtf(ms) / (1.f + ms);
}

// ---------------- agreement + bb update ----------------
__global__ __launch_bounds__(256) void route_upd_k(const float* __restrict__ sq,
                                                   const float* __restrict__ wsum,
                                                   const float* __restrict__ s,
                                                   const float* __restrict__ factor,
                                                   float* __restrict__ bb) {
    int j = blockIdx.x;
    int t = threadIdx.x;
    __shared__ float vs[256];
    {
        int b = t >> 4, o = t & 15;
        vs[t] = s[((size_t)b * 103 + j) * 16 + o] * factor[t];
    }
    __syncthreads();
    const float4* wp = (const float4*)(wsum + ((size_t)t * 103 + j) * 16);
    float4 w0 = wp[0], w1 = wp[1], w2 = wp[2], w3 = wp[3];
    float wv[16] = {w0.x, w0.y, w0.z, w0.w, w1.x, w1.y, w1.z, w1.w,
                    w2.x, w2.y, w2.z, w2.w, w3.x, w3.y, w3.z, w3.w};
    float acc = 0.f;
#pragma unroll
    for (int b = 0; b < 16; ++b) {
        float d = 0.f;
#pragma unroll
        for (int o = 0; o < 16; ++o) d = fmaf(wv[o], vs[b * 16 + o], d);
        acc = fmaf(sq[b * 256 + t], d, acc);
    }
    bb[j * 256 + t] += acc * (1.0f / 16.0f);
}

// ---------------- final v, ba output, f0t[(j*16+o)*16 + b] = v*ba (TRANSPOSED) ----------------
__global__ __launch_bounds__(256) void final_v_k(const float* __restrict__ s,
                                                 const float* __restrict__ factor,
                                                 float* __restrict__ out_ba,
                                                 float* __restrict__ f0t) {
    int idx = blockIdx.x * 256 + threadIdx.x;
    if (idx >= 16 * 103) return;
    int b = idx / 103;
    int j = idx - b * 103;
    const float4* sp = (const float4*)(s + (size_t)idx * 16);
    float4 s0 = sp[0], s1 = sp[1], s2 = sp[2], s3 = sp[3];
    float sv[16] = {s0.x, s0.y, s0.z, s0.w, s1.x, s1.y, s1.z, s1.w,
                    s2.x, s2.y, s2.z, s2.w, s3.x, s3.y, s3.z, s3.w};
    float v[16];
    float nrm2 = 0.f;
#pragma unroll
    for (int o = 0; o < 16; ++o) {
        v[o] = sv[o] * factor[b * 16 + o];
        nrm2 = fmaf(v[o], v[o], nrm2);
    }
    float ba = sqrtf(nrm2);
    out_ba[idx] = ba;
    // f0 transposed: [k=j*16+o][b]
    float* fp = f0t + ((size_t)j << 8) + b;
#pragma unroll
    for (int o = 0; o < 16; ++o) fp[o << 4] = v[o] * ba;
}

// ---------------- FC: partial[..] = sum_{k in chunk} in_t[k][b] * w[k][n] ----------------
// in_t is [K][16] (transposed activations -> contiguous coalesced LDS staging).
// Thread handles 2 adjacent cols, all 16 batches in registers (32 accumulators).
// Flat unroll-4 body (~52 live floats, no spill); TLP (many waves/CU) hides the
// weight-load latency — NO explicit double-buffer (round-1 spill lesson).
// Output: plain stores to per-y-block partial slab (NO atomics); fcred_k sums + bias.
// OUT_T: partial layout [n][16] for fc1/fc2; fc3 keeps [b][N] (final recon layout).
template <bool V2, bool OUT_T>
__global__ __launch_bounds__(256) void fc_k(const float* __restrict__ in,
                                            const float* __restrict__ w,
                                            float* __restrict__ part,
                                            int K, int N, int kchunk) {
    extern __shared__ float sact[];   // [nk][16]
    const int k0 = blockIdx.y * kchunk;
    int nk = K - k0; if (nk > kchunk) nk = kchunk;
    for (int i = threadIdx.x; i < (nk << 4); i += 256)
        sact[i] = in[((size_t)k0 << 4) + i];
    __syncthreads();

    const int c0 = blockIdx.x * 512 + (threadIdx.x << 1);
    const bool st0 = c0 < N;
    const bool st1 = c0 + 1 < N;
    const int c = st0 ? c0 : 0;          // clamp OOB threads (stores guarded)
    const int off1 = st1 ? 1 : 0;        // odd-N tail: duplicate col (a1 discarded)
    const float* wp = w + (size_t)k0 * N + c;
    const size_t Ns = (size_t)N;

    float a0[16], a1[16];
#pragma unroll
    for (int b = 0; b < 16; ++b) { a0[b] = 0.f; a1[b] = 0.f; }

    int k = 0;
    for (; k + 4 <= nk; k += 4) {
        float w00, w01, w10, w11, w20, w21, w30, w31;
        if (V2) {
            float2 q0 = *(const float2*)(wp);
            float2 q1 = *(const float2*)(wp + Ns);
            float2 q2 = *(const float2*)(wp + 2 * Ns);
            float2 q3 = *(const float2*)(wp + 3 * Ns);
            w00 = q0.x; w01 = q0.y; w10 = q1.x; w11 = q1.y;
            w20 = q2.x; w21 = q2.y; w30 = q3.x; w31 = q3.y;
        } else {
            w00 = wp[0];          w01 = wp[off1];
            w10 = wp[Ns];         w11 = wp[Ns + off1];
            w20 = wp[2 * Ns];     w21 = wp[2 * Ns + off1];
            w30 = wp[3 * Ns];     w31 = wp[3 * Ns + off1];
        }
        wp += 4 * Ns;
        const float* s0 = sact + (k << 4);
#pragma unroll
        for (int b = 0; b < 16; ++b) {
            float v0 = s0[b], v1 = s0[16 + b], v2 = s0[32 + b], v3 = s0[48 + b];
            a0[b] = fmaf(v0, w00, a0[b]);
            a1[b] = fmaf(v0, w01, a1[b]);
            a0[b] = fmaf(v1, w10, a0[b]);
            a1[b] = fmaf(v1, w11, a1[b]);
            a0[b] = fmaf(v2, w20, a0[b]);
            a1[b] = fmaf(v2, w21, a1[b]);
            a0[b] = fmaf(v3, w30, a0[b]);
            a1[b] = fmaf(v3, w31, a1[b]);
        }
    }
    for (; k < nk; ++k) {
        float wv0, wv1;
        if (V2) { float2 q = *(const float2*)(wp); wv0 = q.x; wv1 = q.y; }
        else    { wv0 = wp[0]; wv1 = wp[off1]; }
        wp += Ns;
        const float* s0 = sact + (k << 4);
#pragma unroll
        for (int b = 0; b < 16; ++b) {
            a0[b] = fmaf(s0[b], wv0, a0[b]);
            a1[b] = fmaf(s0[b], wv1, a1[b]);
        }
    }

    float* po = part + (size_t)blockIdx.y * (Ns << 4);
    if (OUT_T) {
        // [n][16]: 16 consecutive floats per col -> dwordx4 stores
        if (st0) {
            float* q = po + ((size_t)c << 4);
#pragma unroll
            for (int b = 0; b < 16; ++b) q[b] = a0[b];
        }
        if (st1) {
            float* q = po + ((size_t)(c + 1) << 4);
#pragma unroll
            for (int b = 0; b < 16; ++b) q[b] = a1[b];
        }
    } else {
        // [b][N]: wave writes 128 consecutive floats per b
        if (st0) {
#pragma unroll
            for (int b = 0; b < 16; ++b) po[(size_t)b * Ns + c] = a0[b];
        }
        if (st1) {
#pragma unroll
            for (int b = 0; b < 16; ++b) po[(size_t)b * Ns + c + 1] = a1[b];
        }
    }
}

// ---------------- reduce partials + bias ----------------
// T: out/partials are [n][16], bias idx i>>4 ; else [b][N], bias idx i%N
template <bool T>
__global__ __launch_bounds__(256) void fcred_k(const float* __restrict__ P,
                                               const float* __restrict__ bias,
                                               float* __restrict__ out,
                                               int total, int ny, int N) {
    int i = blockIdx.x * 256 + threadIdx.x;
    if (i >= total) return;
    float sv = T ? bias[i >> 4] : bias[i % N];
    const float* p = P + i;
    for (int y = 0; y < ny; ++y) sv += p[(size_t)y * total];
    out[i] = sv;
}

extern "C" void kernel_launch(void* const* d_in, const int* in_sizes, int n_in,
                              void* d_out, int out_size, void* d_ws, size_t ws_size,
                              hipStream_t stream) {
    const float* x      = (const float*)d_in[0];
    const float* conv_w = (const float*)d_in[1];
    const float* conv_b = (const float*)d_in[2];
    const float* W_caps = (const float*)d_in[3];
    const float* fc1_w  = (const float*)d_in[4];
    const float* fc1_b  = (const float*)d_in[5];
    const float* fc2_w  = (const float*)d_in[6];
    const float* fc2_b  = (const float*)d_in[7];
    const float* fc3_w  = (const float*)d_in[8];
    const float* fc3_b  = (const float*)d_in[9];
    float* out = (float*)d_out;
    float* ws  = (float*)d_ws;

    float* p      = ws + WS_P;
    float* sq     = ws + WS_SQ;
    float* wsum   = ws + WS_WSUM;
    float* bb     = ws + WS_BB;
    float* s      = ws + WS_S;
    float* factor = ws + WS_FACTOR;
    float* f0     = ws + WS_F0;
    float* f1     = ws + WS_F1;
    float* f2     = ws + WS_F2;
    float* part1  = ws + WS_PART1;
    float* part2  = ws + WS_PART2;
    float* part3  = ws + WS_PART3;
    float* ba_out = out;            // 1648
    float* recon  = out + 1648;     // 133488

    init_bb_k<<<103, 256, 0, stream>>>(bb);

    conv_pool_k<<<1024, 256, 0, stream>>>(x, conv_w, conv_b, p);
    squash_p_k<<<16, 256, 0, stream>>>(p, sq);
    wsum_k<<<1648, 256, 0, stream>>>(W_caps, wsum);

    for (int it = 0; it < 3; ++it) {
        route_s_k<<<103, 256, 0, stream>>>(sq, wsum, bb, s);
        factor_k<<<1, 256, 0, stream>>>(s, factor);
        if (it < 2)
            route_upd_k<<<103, 256, 0, stream>>>(sq, wsum, s, factor, bb);
    }
    final_v_k<<<7, 256, 0, stream>>>(s, factor, ba_out, f0);

    // fc1: (16,1648)@(1648,5562); kchunk=40, y=42
    fc_k<true, true><<<dim3(11, 42), 256, 40 * 64, stream>>>(f0, fc1_w, part1, 1648, H1SZ, 40);
    fcred_k<true><<<348, 256, 0, stream>>>(part1, fc1_b, f1, 16 * H1SZ, 42, H1SZ);

    // fc2: (16,5562)@(5562,12514); kchunk=144, y=39
    fc_k<true, true><<<dim3(25, 39), 256, 144 * 64, stream>>>(f1, fc2_w, part2, H1SZ, H2SZ, 144);
    fcred_k<true><<<783, 256, 0, stream>>>(part2, fc2_b, f2, 16 * H2SZ, 39, H2SZ);

    // fc3: (16,12514)@(12514,8343); odd N -> scalar-pair path; kchunk=208, y=61
    fc_k<false, false><<<dim3(17, 61), 256, 208 * 64, stream>>>(f2, fc3_w, part3, H2SZ, RECSZ, 208);
    fcred_k<false><<<522, 256, 0, stream>>>(part3, fc3_b, recon, 16 * RECSZ, 61, RECSZ);
}

// Round 4
// 943.998 us; speedup vs baseline: 2.3026x; 1.0448x over previous
//
#include <hip/hip_runtime.h>
#include <math.h>

#define BATCH 16
#define CIN 103
#define CCONV 256
#define NOUT 103
#define DOUT 16
#define RECSZ 8343
#define H1SZ 5562
#define H2SZ 12514

// ws float offsets
#define WS_P      0         // 16*256
#define WS_SQ     4096      // 16*256
#define WS_WSUM   8192      // 256*103*16 = 421888
#define WS_BB     430080    // 103*256 = 26368
#define WS_S      456448    // 16*103*16 = 26368
#define WS_F0     483072    // f0 TRANSPOSED [1648][16] = 26368
#define WS_F1     509440    // f1 TRANSPOSED [5562][16] = 88992
#define WS_F2     598432    // f2 TRANSPOSED [12514][16] = 200224
#define WS_PART1  798656    // fc1 partials: 42 * 88992  = 3737664
#define WS_PART2  4536320   // fc2 partials: 39 * 200224 = 7808736
#define WS_PART3  12345056  // fc3 partials: 61 * 133488 = 8142768

// ---------------- init: bb = 1 (biases folded into fcred_k) ----------------
__global__ __launch_bounds__(256) void init_bb_k(float* __restrict__ bb) {
    int i = blockIdx.x * 256 + threadIdx.x;
    if (i < 103 * 256) bb[i] = 1.0f;
}

// ---------------- conv (VALID 3x3) + relu + mean pool -> p[b][co] ----------------
__global__ __launch_bounds__(256) void conv_pool_k(const float* __restrict__ x,
                                                   const float* __restrict__ w,
                                                   const float* __restrict__ cb,
                                                   float* __restrict__ p) {
    int b = blockIdx.x >> 6;
    int cob = (blockIdx.x & 63) << 2;
    __shared__ float xs[CIN * 81];
    int t = threadIdx.x;
    for (int i = t; i < CIN * 81; i += 256) xs[i] = x[(size_t)b * CIN * 81 + i];
    __syncthreads();
    int wave = t >> 6, lane = t & 63;
    int co = cob + wave;
    co = __builtin_amdgcn_readfirstlane(co);
    int pos = lane < 49 ? lane : 0;
    int oh = pos / 7, ow = pos % 7;
    const float* wp = w + (size_t)co * CIN * 9;
    const float* xp = xs + oh * 9 + ow;
    float acc = 0.f;
    for (int ci = 0; ci < CIN; ++ci) {
#pragma unroll
        for (int kh = 0; kh < 3; ++kh)
#pragma unroll
            for (int kw = 0; kw < 3; ++kw)
                acc = fmaf(xp[ci * 81 + kh * 9 + kw], wp[ci * 9 + kh * 3 + kw], acc);
    }
    acc += cb[co];
    acc = fmaxf(acc, 0.f);
    if (lane >= 49) acc = 0.f;
#pragma unroll
    for (int off = 32; off; off >>= 1) acc += __shfl_down(acc, off);
    if (lane == 0) p[b * 256 + co] = acc * (1.0f / 49.0f);
}

// ---------------- squash p over c -> sq[b][c] ----------------
__global__ __launch_bounds__(256) void squash_p_k(const float* __restrict__ p, float* __restrict__ sq) {
    int b = blockIdx.x, c = threadIdx.x;
    float v = p[b * 256 + c];
    float ss = v * v;
#pragma unroll
    for (int off = 32; off; off >>= 1) ss += __shfl_down(ss, off);
    __shared__ float red[4];
    if ((c & 63) == 0) red[c >> 6] = ss;
    __syncthreads();
    float ms = red[0] + red[1] + red[2] + red[3];
    float mag = sqrtf(ms);
    sq[b * 256 + c] = v * mag / (1.f + ms);
}

// ---------------- Wsum[c][j][o] = sum_i W_caps[c][j][o][i] ----------------
__global__ __launch_bounds__(256) void wsum_k(const float* __restrict__ Wc, float* __restrict__ wsum) {
    int idx = blockIdx.x * 256 + threadIdx.x;
    const float4* p4 = (const float4*)(Wc + (size_t)idx * 32);
    float s = 0.f;
#pragma unroll
    for (int q = 0; q < 8; ++q) { float4 v = p4[q]; s += v.x + v.y + v.z + v.w; }
    wsum[idx] = s;
}

// ---------------- routing: softmax over c + s[b][j][o] ----------------
__global__ __launch_bounds__(256) void route_s_k(const float* __restrict__ sq,
                                                 const float* __restrict__ wsum,
                                                 const float* __restrict__ bb,
                                                 float* __restrict__ s_out) {
    int j = blockIdx.x;
    int t = threadIdx.x;
    __shared__ float sqst[4096];
    __shared__ float wls[4096];
    __shared__ float cc[256];
    __shared__ float red[8];
    float bv = bb[j * 256 + t];
    for (int i = t; i < 4096; i += 256) {
        sqst[i] = sq[((i & 15) << 8) + (i >> 4)];
        wls[i] = wsum[(size_t)(i >> 4) * (103 * 16) + j * 16 + (i & 15)];
    }
    int wave = t >> 6, lane = t & 63;
    float m = bv;
#pragma unroll
    for (int off = 32; off; off >>= 1) m = fmaxf(m, __shfl_down(m, off));
    if (lane == 0) red[wave] = m;
    __syncthreads();
    m = fmaxf(fmaxf(red[0], red[1]), fmaxf(red[2], red[3]));
    float e = expf(bv - m);
    float ssum = e;
#pragma unroll
    for (int off = 32; off; off >>= 1) ssum += __shfl_down(ssum, off);
    if (lane == 0) red[4 + wave] = ssum;
    __syncthreads();
    ssum = red[4] + red[5] + red[6] + red[7];
    cc[t] = e / ssum;
    __syncthreads();
    for (int i = t; i < 4096; i += 256) sqst[i] *= cc[i >> 4];
    __syncthreads();
    int b = t >> 4, o = t & 15;
    float acc = 0.f;
    for (int c = 0; c < 256; ++c)
        acc = fmaf(sqst[c * 16 + b], wls[c * 16 + o], acc);
    s_out[((size_t)b * 103 + j) * 16 + o] = acc;
}

// ---------------- agreement + bb update (factor computed inline per thread) ----------------
__global__ __launch_bounds__(256) void route_upd_k(const float* __restrict__ sq,
                                                   const float* __restrict__ wsum,
                                                   const float* __restrict__ s,
                                                   float* __restrict__ bb) {
    int j = blockIdx.x;
    int t = threadIdx.x;
    __shared__ float vs[256];
    {
        int b = t >> 4, o = t & 15;
        // factor[b][o]: same fmaf chain as the old factor_k (bitwise identical)
        float ms = 0.f;
        for (int j2 = 0; j2 < 103; ++j2) {
            float v = s[((size_t)b * 103 + j2) * 16 + o];
            ms = fmaf(v, v, ms);
        }
        float fac = sqrtf(ms) / (1.f + ms);
        vs[t] = s[((size_t)b * 103 + j) * 16 + o] * fac;
    }
    __syncthreads();
    const float4* wp = (const float4*)(wsum + ((size_t)t * 103 + j) * 16);
    float4 w0 = wp[0], w1 = wp[1], w2 = wp[2], w3 = wp[3];
    float wv[16] = {w0.x, w0.y, w0.z, w0.w, w1.x, w1.y, w1.z, w1.w,
                    w2.x, w2.y, w2.z, w2.w, w3.x, w3.y, w3.z, w3.w};
    float acc = 0.f;
#pragma unroll
    for (int b = 0; b < 16; ++b) {
        float d = 0.f;
#pragma unroll
        for (int o = 0; o < 16; ++o) d = fmaf(wv[o], vs[b * 16 + o], d);
        acc = fmaf(sq[b * 256 + t], d, acc);
    }
    bb[j * 256 + t] += acc * (1.0f / 16.0f);
}

// ---------------- final v, ba output, f0t (factor table built per block) ----------------
__global__ __launch_bounds__(256) void final_v_k(const float* __restrict__ s,
                                                 float* __restrict__ out_ba,
                                                 float* __restrict__ f0t) {
    __shared__ float fac[256];
    int t = threadIdx.x;
    {
        int b = t >> 4, o = t & 15;
        float ms = 0.f;
        for (int j = 0; j < 103; ++j) {
            float v = s[((size_t)b * 103 + j) * 16 + o];
            ms = fmaf(v, v, ms);
        }
        fac[t] = sqrtf(ms) / (1.f + ms);
    }
    __syncthreads();
    int idx = blockIdx.x * 256 + t;
    if (idx >= 16 * 103) return;
    int b = idx / 103;
    int j = idx - b * 103;
    const float4* sp = (const float4*)(s + (size_t)idx * 16);
    float4 s0 = sp[0], s1 = sp[1], s2 = sp[2], s3 = sp[3];
    float sv[16] = {s0.x, s0.y, s0.z, s0.w, s1.x, s1.y, s1.z, s1.w,
                    s2.x, s2.y, s2.z, s2.w, s3.x, s3.y, s3.z, s3.w};
    float v[16];
    float nrm2 = 0.f;
#pragma unroll
    for (int o = 0; o < 16; ++o) {
        v[o] = sv[o] * fac[b * 16 + o];
        nrm2 = fmaf(v[o], v[o], nrm2);
    }
    float ba = sqrtf(nrm2);
    out_ba[idx] = ba;
    // f0 transposed: [k=j*16+o][b]
    float* fp = f0t + ((size_t)j << 8) + b;
#pragma unroll
    for (int o = 0; o < 16; ++o) fp[o << 4] = v[o] * ba;
}

// ---------------- FC: partial[..] = sum_{k in chunk} in_t[k][b] * w[k][n] ----------------
// in_t is [K][16]. Activation reads are WAVE-UNIFORM (address depends only on
// blockIdx.y / loop index) -> compiler scalarizes to s_load broadcast via SGPRs:
// zero LDS, no staging, no __syncthreads (round-2: LDS-broadcast inner loop was
// issue-bound at ~2-4x the HBM floor). Thread handles 2 adjacent cols x 16 batches.
// Weight loads: float2 (even N) / scalar pair (odd N, fc3), coalesced.
// Output: plain stores to per-y-block partial slab; fcred_k sums + bias.
template <bool V2, bool OUT_T>
__global__ __launch_bounds__(256) void fc_k(const float* __restrict__ in,
                                            const float* __restrict__ w,
                                            float* __restrict__ part,
                                            int K, int N, int kchunk) {
    const int k0 = blockIdx.y * kchunk;
    int nk = K - k0; if (nk > kchunk) nk = kchunk;

    const int c0 = blockIdx.x * 512 + (threadIdx.x << 1);
    const bool st0 = c0 < N;
    const bool st1 = c0 + 1 < N;
    const int c = st0 ? c0 : 0;          // clamp OOB threads (stores guarded)
    const int off1 = st1 ? 1 : 0;        // odd-N tail: duplicate col (a1 discarded)
    const float* wp = w + (size_t)k0 * N + c;
    const float* ap = in + ((size_t)k0 << 4);   // uniform activation base
    const size_t Ns = (size_t)N;

    float a0[16], a1[16];
#pragma unroll
    for (int b = 0; b < 16; ++b) { a0[b] = 0.f; a1[b] = 0.f; }

    int k = 0;
    for (; k + 4 <= nk; k += 4) {
        float w00, w01, w10, w11, w20, w21, w30, w31;
        if (V2) {
            float2 q0 = *(const float2*)(wp);
            float2 q1 = *(const float2*)(wp + Ns);
            float2 q2 = *(const float2*)(wp + 2 * Ns);
            float2 q3 = *(const float2*)(wp + 3 * Ns);
            w00 = q0.x; w01 = q0.y; w10 = q1.x; w11 = q1.y;
            w20 = q2.x; w21 = q2.y; w30 = q3.x; w31 = q3.y;
        } else {
            w00 = wp[0];          w01 = wp[off1];
            w10 = wp[Ns];         w11 = wp[Ns + off1];
            w20 = wp[2 * Ns];     w21 = wp[2 * Ns + off1];
            w30 = wp[3 * Ns];     w31 = wp[3 * Ns + off1];
        }
        wp += 4 * Ns;
        const float* a = ap + (k << 4);   // uniform -> s_load
#pragma unroll
        for (int b = 0; b < 16; ++b) {
            float v0 = a[b], v1 = a[16 + b], v2 = a[32 + b], v3 = a[48 + b];
            a0[b] = fmaf(v0, w00, a0[b]);
            a1[b] = fmaf(v0, w01, a1[b]);
            a0[b] = fmaf(v1, w10, a0[b]);
            a1[b] = fmaf(v1, w11, a1[b]);
            a0[b] = fmaf(v2, w20, a0[b]);
            a1[b] = fmaf(v2, w21, a1[b]);
            a0[b] = fmaf(v3, w30, a0[b]);
            a1[b] = fmaf(v3, w31, a1[b]);
        }
    }
    for (; k < nk; ++k) {
        float wv0, wv1;
        if (V2) { float2 q = *(const float2*)(wp); wv0 = q.x; wv1 = q.y; }
        else    { wv0 = wp[0]; wv1 = wp[off1]; }
        wp += Ns;
        const float* a = ap + (k << 4);
#pragma unroll
        for (int b = 0; b < 16; ++b) {
            a0[b] = fmaf(a[b], wv0, a0[b]);
            a1[b] = fmaf(a[b], wv1, a1[b]);
        }
    }

    float* po = part + (size_t)blockIdx.y * (Ns << 4);
    if (OUT_T) {
        // [n][16]: 16 consecutive floats per col -> dwordx4 stores
        if (st0) {
            float* q = po + ((size_t)c << 4);
#pragma unroll
            for (int b = 0; b < 16; ++b) q[b] = a0[b];
        }
        if (st1) {
            float* q = po + ((size_t)(c + 1) << 4);
#pragma unroll
            for (int b = 0; b < 16; ++b) q[b] = a1[b];
        }
    } else {
        // [b][N]: wave writes 128 consecutive floats per b
        if (st0) {
#pragma unroll
            for (int b = 0; b < 16; ++b) po[(size_t)b * Ns + c] = a0[b];
        }
        if (st1) {
#pragma unroll
            for (int b = 0; b < 16; ++b) po[(size_t)b * Ns + c + 1] = a1[b];
        }
    }
}

// ---------------- reduce partials + bias ----------------
// T: out/partials are [n][16], bias idx i>>4 ; else [b][N], bias idx i%N
template <bool T>
__global__ __launch_bounds__(256) void fcred_k(const float* __restrict__ P,
                                               const float* __restrict__ bias,
                                               float* __restrict__ out,
                                               int total, int ny, int N) {
    int i = blockIdx.x * 256 + threadIdx.x;
    if (i >= total) return;
    float sv = T ? bias[i >> 4] : bias[i % N];
    const float* p = P + i;
    for (int y = 0; y < ny; ++y) sv += p[(size_t)y * total];
    out[i] = sv;
}

extern "C" void kernel_launch(void* const* d_in, const int* in_sizes, int n_in,
                              void* d_out, int out_size, void* d_ws, size_t ws_size,
                              hipStream_t stream) {
    const float* x      = (const float*)d_in[0];
    const float* conv_w = (const float*)d_in[1];
    const float* conv_b = (const float*)d_in[2];
    const float* W_caps = (const float*)d_in[3];
    const float* fc1_w  = (const float*)d_in[4];
    const float* fc1_b  = (const float*)d_in[5];
    const float* fc2_w  = (const float*)d_in[6];
    const float* fc2_b  = (const float*)d_in[7];
    const float* fc3_w  = (const float*)d_in[8];
    const float* fc3_b  = (const float*)d_in[9];
    float* out = (float*)d_out;
    float* ws  = (float*)d_ws;

    float* p      = ws + WS_P;
    float* sq     = ws + WS_SQ;
    float* wsum   = ws + WS_WSUM;
    float* bb     = ws + WS_BB;
    float* s      = ws + WS_S;
    float* f0     = ws + WS_F0;
    float* f1     = ws + WS_F1;
    float* f2     = ws + WS_F2;
    float* part1  = ws + WS_PART1;
    float* part2  = ws + WS_PART2;
    float* part3  = ws + WS_PART3;
    float* ba_out = out;            // 1648
    float* recon  = out + 1648;     // 133488

    init_bb_k<<<103, 256, 0, stream>>>(bb);

    conv_pool_k<<<1024, 256, 0, stream>>>(x, conv_w, conv_b, p);
    squash_p_k<<<16, 256, 0, stream>>>(p, sq);
    wsum_k<<<1648, 256, 0, stream>>>(W_caps, wsum);

    for (int it = 0; it < 3; ++it) {
        route_s_k<<<103, 256, 0, stream>>>(sq, wsum, bb, s);
        if (it < 2)
            route_upd_k<<<103, 256, 0, stream>>>(sq, wsum, s, bb);
    }
    final_v_k<<<7, 256, 0, stream>>>(s, ba_out, f0);

    // fc1: (16,1648)@(1648,5562); kchunk=40, y=42
    fc_k<true, true><<<dim3(11, 42), 256, 0, stream>>>(f0, fc1_w, part1, 1648, H1SZ, 40);
    fcred_k<true><<<348, 256, 0, stream>>>(part1, fc1_b, f1, 16 * H1SZ, 42, H1SZ);

    // fc2: (16,5562)@(5562,12514); kchunk=144, y=39
    fc_k<true, true><<<dim3(25, 39), 256, 0, stream>>>(f1, fc2_w, part2, H1SZ, H2SZ, 144);
    fcred_k<true><<<783, 256, 0, stream>>>(part2, fc2_b, f2, 16 * H2SZ, 39, H2SZ);

    // fc3: (16,12514)@(12514,8343); odd N -> scalar-pair path; kchunk=208, y=61
    fc_k<false, false><<<dim3(17, 61), 256, 0, stream>>>(f2, fc3_w, part3, H2SZ, RECSZ, 208);
    fcred_k<false><<<522, 256, 0, stream>>>(part3, fc3_b, recon, 16 * RECSZ, 61, RECSZ);
}